// Round 2
// baseline (1512.658 us; speedup 1.0000x reference)
//
#include <hip/hip_runtime.h>

#define E_ 8
#define C_ 1024
#define H_ 2048
#define B_ 8
#define T_ 1024
#define NGRP 64          // B_*E_
#define NROWS 16384      // B_*T_*K

typedef __bf16 bf16x8 __attribute__((ext_vector_type(8)));
typedef float f32x4 __attribute__((ext_vector_type(4)));
typedef unsigned short u16;

__device__ __forceinline__ u16 f2bf(float f) {
  unsigned u = __float_as_uint(f);
  u += 0x7FFFu + ((u >> 16) & 1u);   // RNE; inputs finite
  return (u16)(u >> 16);
}

// async global->LDS, 16B per lane; lds dst is wave-uniform base + lane*16
__device__ __forceinline__ void gl16(const u16* g, u16* l) {
  __builtin_amdgcn_global_load_lds(
      (const __attribute__((address_space(1))) void*)g,
      (__attribute__((address_space(3))) void*)l, 16, 0, 0);
}

// ---------- weights: in [E][R][S] f32 -> out [E][S][R] bf16 (transpose) ----------
__global__ __launch_bounds__(256) void k_wt(const float* __restrict__ in,
                                            u16* __restrict__ out, int R, int S) {
  __shared__ u16 tile[64][66];
  int e = blockIdx.z;
  int s0 = blockIdx.x * 64, r0 = blockIdx.y * 64;
  int tx = threadIdx.x & 15, ty = threadIdx.x >> 4;
  const float* src = in + ((size_t)e * R + r0) * S + s0;
  #pragma unroll
  for (int i = 0; i < 4; ++i) {
    int rr = i * 16 + ty;
    float4 v = *reinterpret_cast<const float4*>(src + (size_t)rr * S + tx * 4);
    tile[rr][tx * 4 + 0] = f2bf(v.x);
    tile[rr][tx * 4 + 1] = f2bf(v.y);
    tile[rr][tx * 4 + 2] = f2bf(v.z);
    tile[rr][tx * 4 + 3] = f2bf(v.w);
  }
  __syncthreads();
  u16* dst = out + ((size_t)e * S + s0) * R + r0;
  #pragma unroll
  for (int i = 0; i < 4; ++i) {
    int ss = i * 16 + ty;
    ushort4 o;
    o.x = tile[tx * 4 + 0][ss];
    o.y = tile[tx * 4 + 1][ss];
    o.z = tile[tx * 4 + 2][ss];
    o.w = tile[tx * 4 + 3][ss];
    *reinterpret_cast<ushort4*>(dst + (size_t)ss * R + tx * 4) = o;
  }
}

// ---------- router: one wave per token; emits x bf16 + inverse index ----------
__global__ __launch_bounds__(256) void k_router(const float* __restrict__ x,
                                                const float* __restrict__ rw,
                                                u16* __restrict__ xb,
                                                int* __restrict__ counts,
                                                int* __restrict__ tok,
                                                float* __restrict__ pw,
                                                int* __restrict__ inv) {
  int lane = threadIdx.x & 63;
  int tt = blockIdx.x * 4 + (threadIdx.x >> 6);    // token id 0..8191
  const float* xr = x + (size_t)tt * C_;
  u16* xo = xb + (size_t)tt * C_;
  float acc[8] = {0, 0, 0, 0, 0, 0, 0, 0};
  for (int j = 0; j < 16; ++j) {
    int c = j * 64 + lane;
    float xv = xr[c];
    xo[c] = f2bf(xv);
    float4 r0 = reinterpret_cast<const float4*>(rw + c * 8)[0];
    float4 r1 = reinterpret_cast<const float4*>(rw + c * 8)[1];
    acc[0] += xv * r0.x; acc[1] += xv * r0.y; acc[2] += xv * r0.z; acc[3] += xv * r0.w;
    acc[4] += xv * r1.x; acc[5] += xv * r1.y; acc[6] += xv * r1.z; acc[7] += xv * r1.w;
  }
  #pragma unroll
  for (int e = 0; e < 8; ++e)
    #pragma unroll
    for (int off = 32; off; off >>= 1)
      acc[e] += __shfl_xor(acc[e], off);
  if (lane == 0) {
    int b = tt >> 10, t = tt & (T_ - 1);
    int e0 = 0;
    #pragma unroll
    for (int e = 1; e < 8; ++e) if (acc[e] > acc[e0]) e0 = e;   // ties -> lower idx
    int e1 = -1;
    #pragma unroll
    for (int e = 0; e < 8; ++e)
      if (e != e0 && (e1 < 0 || acc[e] > acc[e1])) e1 = e;
    float l0 = acc[e0], l1 = acc[e1];
    float p0 = 1.f / (1.f + expf(l1 - l0));
    float p1 = 1.f / (1.f + expf(l0 - l1));
    int g0 = b * 8 + e0, g1 = b * 8 + e1;
    int s0 = atomicAdd(&counts[g0], 1);
    tok[g0 * T_ + s0] = t; pw[g0 * T_ + s0] = p0;
    int s1 = atomicAdd(&counts[g1], 1);
    tok[g1 * T_ + s1] = t; pw[g1 * T_ + s1] = p1;
    inv[tt * 2 + 0] = g0 * T_ + s0;
    inv[tt * 2 + 1] = g1 * T_ + s1;
  }
}

// ---------- exclusive prefix over 64 counts ----------
__global__ void k_prefix(const int* __restrict__ counts, int* __restrict__ offsets) {
  if (threadIdx.x == 0) {
    int s = 0;
    for (int i = 0; i < NGRP; ++i) { offsets[i] = s; s += counts[i]; }
    offsets[NGRP] = s;
  }
}

// ---------- GEMM1: inter = (Xe@Wfc+bfc) * silu(Xe@Wg+bg), bf16 out ----------
// BM=128 x BN=64, dual-B, BK=64, global_load_lds(16B).
// Both-sides XOR swizzle (16B slot ^= row&7): inverse-swizzled global source,
// swizzled ds_read -> conflict-free b128 fragment reads (rule #21 / m201).
__global__ __launch_bounds__(256, 5) void k_ffn1(
    const u16* __restrict__ xb, const u16* __restrict__ wfcT, const u16* __restrict__ wgT,
    const float* __restrict__ bfc, const float* __restrict__ bg,
    const int* __restrict__ counts, const int* __restrict__ offsets,
    const int* __restrict__ tok, u16* __restrict__ inter) {
  int bid = blockIdx.x;
  int e = bid & 7;
  int r = bid >> 3;                 // [0,2048)
  int chunk = r >> 9;               // [0,4)   8-coltile chunk (2MB weights -> L2)
  int rr = r & 511;
  int brt = rr >> 3;                // [0,64)  (b, rowtile)
  int col = (chunk << 3) | (rr & 7);
  int b = brt >> 3, rt = brt & 7;
  int g = b * 8 + e;
  int n = counts[g];
  int row0 = rt * 128;
  if (row0 >= n) return;
  int col0 = col * 64;

  __shared__ u16 As[128 * 64];      // 16 KB
  __shared__ u16 Bf[64 * 64];       // 8 KB
  __shared__ u16 Bg[64 * 64];       // 8 KB

  int tid = threadIdx.x;
  int lane = tid & 63, wid = tid >> 6;
  int wr = wid >> 1, wc = wid & 1;
  int fr = lane & 15, fq = lane >> 4;
  int q = fr & 7;

  // ---- staging (sources pre-swizzled; LDS dest linear) ----
  // A: chunk ck covers row=ck>>3, 16B-slot=ck&7 ; source slot = (ck&7)^(row&7)
  const u16* sA[4];
  {
    #pragma unroll
    for (int i = 0; i < 4; ++i) {
      int ck = (wid * 4 + i) * 64 + lane;
      int row = ck >> 3;
      int kc = ((ck & 7) ^ (row & 7)) * 8;
      int slot = row0 + row;
      int t = tok[g * T_ + (slot < n ? slot : n - 1)];
      sA[i] = xb + ((size_t)(b * T_ + t)) * C_ + kc;
    }
  }
  int ckB = (wid * 2) * 64 + lane;
  int rowB = ckB >> 3;
  int kcB = ((ckB & 7) ^ (rowB & 7)) * 8;
  const u16* sF0 = wfcT + ((size_t)e * H_ + col0 + rowB) * C_ + kcB;
  const u16* sG0 = wgT + ((size_t)e * H_ + col0 + rowB) * C_ + kcB;
  u16* lA0 = (u16*)As + (size_t)(wid * 4) * 512;
  u16* lF0 = (u16*)Bf + (size_t)(wid * 2) * 512;
  u16* lG0 = (u16*)Bg + (size_t)(wid * 2) * 512;

  f32x4 ah[4][2] = {}; f32x4 ag[4][2] = {};

  for (int kt = 0; kt < C_; kt += 64) {
    __syncthreads();
    #pragma unroll
    for (int i = 0; i < 4; ++i) gl16(sA[i] + kt, lA0 + i * 512);
    gl16(sF0 + kt, lF0); gl16(sF0 + 8 * C_ + kt, lF0 + 512);
    gl16(sG0 + kt, lG0); gl16(sG0 + 8 * C_ + kt, lG0 + 512);
    __syncthreads();
    #pragma unroll
    for (int kk = 0; kk < 2; ++kk) {
      int so = ((kk * 4 + fq) ^ q) * 8;     // swizzled 16B slot -> u16 offset
      bf16x8 a[4], f[2], gg[2];
      #pragma unroll
      for (int m = 0; m < 4; ++m)
        a[m] = *reinterpret_cast<const bf16x8*>(&As[(wr * 64 + m * 16 + fr) * 64 + so]);
      #pragma unroll
      for (int j = 0; j < 2; ++j) {
        f[j]  = *reinterpret_cast<const bf16x8*>(&Bf[(wc * 32 + j * 16 + fr) * 64 + so]);
        gg[j] = *reinterpret_cast<const bf16x8*>(&Bg[(wc * 32 + j * 16 + fr) * 64 + so]);
      }
      #pragma unroll
      for (int m = 0; m < 4; ++m)
        #pragma unroll
        for (int j = 0; j < 2; ++j) {
          ah[m][j] = __builtin_amdgcn_mfma_f32_16x16x32_bf16(a[m], f[j],  ah[m][j], 0, 0, 0);
          ag[m][j] = __builtin_amdgcn_mfma_f32_16x16x32_bf16(a[m], gg[j], ag[m][j], 0, 0, 0);
        }
    }
  }
  int base = offsets[g];
  #pragma unroll
  for (int m = 0; m < 4; ++m) {
    #pragma unroll
    for (int rj = 0; rj < 4; ++rj) {
      int slot = row0 + wr * 64 + m * 16 + fq * 4 + rj;
      if (slot < n) {
        size_t rowb = (size_t)(base + slot) * H_;
        #pragma unroll
        for (int j = 0; j < 2; ++j) {
          int hc = col0 + wc * 32 + j * 16 + fr;
          float h  = ah[m][j][rj] + bfc[e * H_ + hc];
          float gp = ag[m][j][rj] + bg[e * H_ + hc];
          inter[rowb + hc] = f2bf(h * gp / (1.f + expf(-gp)));   // h * silu(gp)
        }
      }
    }
  }
}

// ---------- GEMM2: obuf = inter@Wproj + bp  (non-atomic, compacted rows) ----------
__global__ __launch_bounds__(256) void k_ffn2(
    const u16* __restrict__ inter, const u16* __restrict__ wpT,
    const float* __restrict__ bp,
    const int* __restrict__ counts, const int* __restrict__ offsets,
    float* __restrict__ obuf) {
  int bid = blockIdx.x;
  int e = bid & 7;
  int r = bid >> 3;                 // [0,512)
  int brt = r >> 3;                 // [0,64) (b,rowtile) outer; col inner (A reuse)
  int col = r & 7;
  int b = brt >> 3, rt = brt & 7;
  int g = b * 8 + e;
  int n = counts[g];
  int row0 = rt * 128;
  if (row0 >= n) return;
  int col0 = col * 128;
  int base = offsets[g];

  __shared__ u16 As[128 * 64];      // 16 KB
  __shared__ u16 Bs[128 * 64];      // 16 KB

  int tid = threadIdx.x;
  int lane = tid & 63, wid = tid >> 6;
  int wr = wid >> 1, wc = wid & 1;
  int fr = lane & 15, fq = lane >> 4;
  int q = fr & 7;

  const u16* sA[4];
  {
    #pragma unroll
    for (int i = 0; i < 4; ++i) {
      int ck = (wid * 4 + i) * 64 + lane;
      int row = ck >> 3;
      int kc = ((ck & 7) ^ (row & 7)) * 8;
      int slot = row0 + row;
      int rg = base + (slot < n ? slot : n - 1);   // clamp into valid compacted rows
      sA[i] = inter + (size_t)rg * H_ + kc;
    }
  }
  int ckB = (wid * 4) * 64 + lane;
  int rowB = ckB >> 3;
  int kcB = ((ckB & 7) ^ (rowB & 7)) * 8;
  const u16* sB0 = wpT + ((size_t)e * C_ + col0 + rowB) * H_ + kcB;
  u16* lA0 = (u16*)As + (size_t)(wid * 4) * 512;
  u16* lB0 = (u16*)Bs + (size_t)(wid * 4) * 512;

  f32x4 acc[4][4] = {};

  for (int kt = 0; kt < H_; kt += 64) {
    __syncthreads();
    #pragma unroll
    for (int i = 0; i < 4; ++i) {
      gl16(sA[i] + kt, lA0 + i * 512);
      gl16(sB0 + (size_t)i * 8 * H_ + kt, lB0 + i * 512);
    }
    __syncthreads();
    #pragma unroll
    for (int kk = 0; kk < 2; ++kk) {
      int so = ((kk * 4 + fq) ^ q) * 8;
      bf16x8 a[4], bb[4];
      #pragma unroll
      for (int m = 0; m < 4; ++m)
        a[m] = *reinterpret_cast<const bf16x8*>(&As[(wr * 64 + m * 16 + fr) * 64 + so]);
      #pragma unroll
      for (int j = 0; j < 4; ++j)
        bb[j] = *reinterpret_cast<const bf16x8*>(&Bs[(wc * 64 + j * 16 + fr) * 64 + so]);
      #pragma unroll
      for (int m = 0; m < 4; ++m)
        #pragma unroll
        for (int j = 0; j < 4; ++j)
          acc[m][j] = __builtin_amdgcn_mfma_f32_16x16x32_bf16(a[m], bb[j], acc[m][j], 0, 0, 0);
    }
  }
  #pragma unroll
  for (int m = 0; m < 4; ++m) {
    #pragma unroll
    for (int rj = 0; rj < 4; ++rj) {
      int slot = row0 + wr * 64 + m * 16 + fq * 4 + rj;
      if (slot < n) {
        float* orow = obuf + (size_t)(base + slot) * C_;
        #pragma unroll
        for (int j = 0; j < 4; ++j) {
          int cc = col0 + wc * 64 + j * 16 + fr;
          orow[cc] = acc[m][j][rj] + bp[e * C_ + cc];
        }
      }
    }
  }
}

// ---------- combine: y[t] = p0*obuf[r0] + p1*obuf[r1] ----------
__global__ __launch_bounds__(256) void k_combine(const float* __restrict__ obuf,
                                                 const int* __restrict__ offsets,
                                                 const int* __restrict__ inv,
                                                 const float* __restrict__ pw,
                                                 float* __restrict__ y) {
  int tt = blockIdx.x;
  int c = threadIdx.x * 4;
  int i0 = inv[tt * 2 + 0], i1 = inv[tt * 2 + 1];
  int r0 = offsets[i0 >> 10] + (i0 & (T_ - 1));
  int r1 = offsets[i1 >> 10] + (i1 & (T_ - 1));
  float p0 = pw[i0], p1 = pw[i1];
  float4 a = *reinterpret_cast<const float4*>(obuf + (size_t)r0 * C_ + c);
  float4 bv = *reinterpret_cast<const float4*>(obuf + (size_t)r1 * C_ + c);
  float4 o;
  o.x = p0 * a.x + p1 * bv.x;
  o.y = p0 * a.y + p1 * bv.y;
  o.z = p0 * a.z + p1 * bv.z;
  o.w = p0 * a.w + p1 * bv.w;
  *reinterpret_cast<float4*>(y + (size_t)tt * C_ + c) = o;
}

extern "C" void kernel_launch(void* const* d_in, const int* in_sizes, int n_in,
                              void* d_out, int out_size, void* d_ws, size_t ws_size,
                              hipStream_t stream) {
  const float* x   = (const float*)d_in[0];
  const float* rw  = (const float*)d_in[1];
  const float* wfc = (const float*)d_in[2];
  const float* bfc = (const float*)d_in[3];
  const float* wg  = (const float*)d_in[4];
  const float* bg  = (const float*)d_in[5];
  const float* wp  = (const float*)d_in[6];
  const float* bp  = (const float*)d_in[7];
  float* y = (float*)d_out;

  char* ws = (char*)d_ws;
  // ws layout (bytes). obuf aliases wfcT+wgT (dead after k_ffn1); total ~177MB.
  const size_t OFF_COUNTS  = 0;                        // 64 ints
  const size_t OFF_OFFSETS = 1024;                     // 65 ints
  const size_t OFF_TOK     = 2048;                     // 256 KB
  const size_t OFF_PW      = OFF_TOK + 262144;         // 256 KB
  const size_t OFF_INV     = OFF_PW + 262144;          // 128 KB
  const size_t OFF_XB      = OFF_INV + 131072;         // 16 MB bf16 x
  const size_t OFF_WPT     = OFF_XB + (size_t)B_ * T_ * C_ * 2;     // 32 MB
  const size_t OFF_INTER   = OFF_WPT + (size_t)E_ * H_ * C_ * 2;    // 64 MB bf16
  const size_t OFF_WFCT    = OFF_INTER + (size_t)NROWS * H_ * 2;    // 32 MB
  const size_t OFF_WGT     = OFF_WFCT + (size_t)E_ * C_ * H_ * 2;   // 32 MB
  const size_t OFF_OBUF    = OFF_WFCT;                 // 64 MB f32, aliases wfcT+wgT
  int*   counts  = (int*)(ws + OFF_COUNTS);
  int*   offsets = (int*)(ws + OFF_OFFSETS);
  int*   tok     = (int*)(ws + OFF_TOK);
  float* pw      = (float*)(ws + OFF_PW);
  int*   inv     = (int*)(ws + OFF_INV);
  u16*   xb      = (u16*)(ws + OFF_XB);
  u16*   wpT     = (u16*)(ws + OFF_WPT);
  u16*   inter   = (u16*)(ws + OFF_INTER);
  u16*   wfcT    = (u16*)(ws + OFF_WFCT);
  u16*   wgT     = (u16*)(ws + OFF_WGT);
  float* obuf    = (float*)(ws + OFF_OBUF);

  hipMemsetAsync(counts, 0, 256, stream);

  k_wt<<<dim3(H_ / 64, C_ / 64, E_), 256, 0, stream>>>(wfc, wfcT, C_, H_);
  k_wt<<<dim3(H_ / 64, C_ / 64, E_), 256, 0, stream>>>(wg, wgT, C_, H_);
  k_wt<<<dim3(C_ / 64, H_ / 64, E_), 256, 0, stream>>>(wp, wpT, H_, C_);
  k_router<<<(B_ * T_) / 4, 256, 0, stream>>>(x, rw, xb, counts, tok, pw, inv);
  k_prefix<<<1, 64, 0, stream>>>(counts, offsets);
  k_ffn1<<<E_ * 4 * 64 * 8, 256, 0, stream>>>(          // 16384 blocks
      xb, wfcT, wgT, bfc, bg, counts, offsets, tok, inter);
  k_ffn2<<<E_ * 64 * 8, 256, 0, stream>>>(              // 4096 blocks
      inter, wpT, bp, counts, offsets, obuf);
  k_combine<<<B_ * T_, 256, 0, stream>>>(obuf, offsets, inv, pw, y);
  (void)in_sizes; (void)n_in; (void)ws_size;
}

// Round 3
// 628.863 us; speedup vs baseline: 2.4054x; 2.4054x over previous
//
#include <hip/hip_runtime.h>

#define E_ 8
#define C_ 1024
#define H_ 2048
#define B_ 8
#define T_ 1024
#define NGRP 64          // B_*E_
#define NROWS 16384      // B_*T_*K

typedef __bf16 bf16x8 __attribute__((ext_vector_type(8)));
typedef float f32x4 __attribute__((ext_vector_type(4)));
typedef unsigned short u16;

__device__ __forceinline__ u16 f2bf(float f) {
  unsigned u = __float_as_uint(f);
  u += 0x7FFFu + ((u >> 16) & 1u);   // RNE; inputs finite
  return (u16)(u >> 16);
}

// async global->LDS, 16B per lane; lds dst is wave-uniform base + lane*16
__device__ __forceinline__ void gl16(const u16* g, u16* l) {
  __builtin_amdgcn_global_load_lds(
      (const __attribute__((address_space(1))) void*)g,
      (__attribute__((address_space(3))) void*)l, 16, 0, 0);
}

// ---------- weights: in [E][R][S] f32 -> out [E][S][R] bf16 (transpose) ----------
__global__ __launch_bounds__(256) void k_wt(const float* __restrict__ in,
                                            u16* __restrict__ out, int R, int S) {
  __shared__ u16 tile[64][66];
  int e = blockIdx.z;
  int s0 = blockIdx.x * 64, r0 = blockIdx.y * 64;
  int tx = threadIdx.x & 15, ty = threadIdx.x >> 4;
  const float* src = in + ((size_t)e * R + r0) * S + s0;
  #pragma unroll
  for (int i = 0; i < 4; ++i) {
    int rr = i * 16 + ty;
    float4 v = *reinterpret_cast<const float4*>(src + (size_t)rr * S + tx * 4);
    tile[rr][tx * 4 + 0] = f2bf(v.x);
    tile[rr][tx * 4 + 1] = f2bf(v.y);
    tile[rr][tx * 4 + 2] = f2bf(v.z);
    tile[rr][tx * 4 + 3] = f2bf(v.w);
  }
  __syncthreads();
  u16* dst = out + ((size_t)e * S + s0) * R + r0;
  #pragma unroll
  for (int i = 0; i < 4; ++i) {
    int ss = i * 16 + ty;
    ushort4 o;
    o.x = tile[tx * 4 + 0][ss];
    o.y = tile[tx * 4 + 1][ss];
    o.z = tile[tx * 4 + 2][ss];
    o.w = tile[tx * 4 + 3][ss];
    *reinterpret_cast<ushort4*>(dst + (size_t)ss * R + tx * 4) = o;
  }
}

// ---------- router: one wave per token; emits x bf16 + inverse index ----------
__global__ __launch_bounds__(256) void k_router(const float* __restrict__ x,
                                                const float* __restrict__ rw,
                                                u16* __restrict__ xb,
                                                int* __restrict__ counts,
                                                int* __restrict__ tok,
                                                float* __restrict__ pw,
                                                int* __restrict__ inv) {
  int lane = threadIdx.x & 63;
  int tt = blockIdx.x * 4 + (threadIdx.x >> 6);    // token id 0..8191
  const float* xr = x + (size_t)tt * C_;
  u16* xo = xb + (size_t)tt * C_;
  float acc[8] = {0, 0, 0, 0, 0, 0, 0, 0};
  for (int j = 0; j < 16; ++j) {
    int c = j * 64 + lane;
    float xv = xr[c];
    xo[c] = f2bf(xv);
    float4 r0 = reinterpret_cast<const float4*>(rw + c * 8)[0];
    float4 r1 = reinterpret_cast<const float4*>(rw + c * 8)[1];
    acc[0] += xv * r0.x; acc[1] += xv * r0.y; acc[2] += xv * r0.z; acc[3] += xv * r0.w;
    acc[4] += xv * r1.x; acc[5] += xv * r1.y; acc[6] += xv * r1.z; acc[7] += xv * r1.w;
  }
  #pragma unroll
  for (int e = 0; e < 8; ++e)
    #pragma unroll
    for (int off = 32; off; off >>= 1)
      acc[e] += __shfl_xor(acc[e], off);
  if (lane == 0) {
    int b = tt >> 10, t = tt & (T_ - 1);
    int e0 = 0;
    #pragma unroll
    for (int e = 1; e < 8; ++e) if (acc[e] > acc[e0]) e0 = e;   // ties -> lower idx
    int e1 = -1;
    #pragma unroll
    for (int e = 0; e < 8; ++e)
      if (e != e0 && (e1 < 0 || acc[e] > acc[e1])) e1 = e;
    float l0 = acc[e0], l1 = acc[e1];
    float p0 = 1.f / (1.f + expf(l1 - l0));
    float p1 = 1.f / (1.f + expf(l0 - l1));
    int g0 = b * 8 + e0, g1 = b * 8 + e1;
    int s0 = atomicAdd(&counts[g0], 1);
    tok[g0 * T_ + s0] = t; pw[g0 * T_ + s0] = p0;
    int s1 = atomicAdd(&counts[g1], 1);
    tok[g1 * T_ + s1] = t; pw[g1 * T_ + s1] = p1;
    inv[tt * 2 + 0] = g0 * T_ + s0;
    inv[tt * 2 + 1] = g1 * T_ + s1;
  }
}

// ---------- exclusive prefix over 64 counts ----------
__global__ void k_prefix(const int* __restrict__ counts, int* __restrict__ offsets) {
  if (threadIdx.x == 0) {
    int s = 0;
    for (int i = 0; i < NGRP; ++i) { offsets[i] = s; s += counts[i]; }
    offsets[NGRP] = s;
  }
}

// ---------- GEMM1: inter = (Xe@Wfc+bfc) * silu(Xe@Wg+bg), bf16 out ----------
// BM=128 x BN=64, dual-B, BK=64. Double-buffered LDS (64KB -> hard cap 2 blk/CU,
// keeps per-XCD L2 working set ~3MB) + counted-vmcnt pipeline (T3/T4).
// Both-sides XOR swizzle: conflict-free ds_read_b128 (verified r2: conflicts=0).
__global__ __launch_bounds__(256) void k_ffn1(
    const u16* __restrict__ xb, const u16* __restrict__ wfcT, const u16* __restrict__ wgT,
    const float* __restrict__ bfc, const float* __restrict__ bg,
    const int* __restrict__ counts, const int* __restrict__ offsets,
    const int* __restrict__ tok, u16* __restrict__ inter) {
  int bid = blockIdx.x;
  int e = bid & 7;                  // XCD pin
  int r = bid >> 3;                 // [0,2048)
  int chunk = r >> 8;               // [0,8)  4-coltile chunk (1MB weights -> L2)
  int rr = r & 255;
  int brt = rr >> 2;                // [0,64) (b, rowtile); col inner (A reuse)
  int col = chunk * 4 + (rr & 3);   // [0,32)
  int b = brt >> 3, rt = brt & 7;
  int g = b * 8 + e;
  int n = counts[g];
  int row0 = rt * 128;
  if (row0 >= n) return;
  int col0 = col * 64;

  __shared__ u16 As[2][128 * 64];   // 2 x 16 KB
  __shared__ u16 Bf[2][64 * 64];    // 2 x 8 KB
  __shared__ u16 Bg[2][64 * 64];    // 2 x 8 KB   total 64 KB

  int tid = threadIdx.x;
  int lane = tid & 63, wid = tid >> 6;
  int wr = wid >> 1, wc = wid & 1;
  int fr = lane & 15, fq = lane >> 4;
  int q = fr & 7;

  // staging sources, pre-swizzled: chunk ck -> row=ck>>3, src 16B-slot=(ck&7)^(row&7)
  const u16* sA[4];
  #pragma unroll
  for (int i = 0; i < 4; ++i) {
    int ck = (wid * 4 + i) * 64 + lane;
    int row = ck >> 3;
    int kc = ((ck & 7) ^ (row & 7)) * 8;
    int slot = row0 + row;
    int t = tok[g * T_ + (slot < n ? slot : n - 1)];
    sA[i] = xb + ((size_t)(b * T_ + t)) * C_ + kc;
  }
  int ckB = (wid * 2) * 64 + lane;
  int rowB = ckB >> 3;
  int kcB = ((ckB & 7) ^ (rowB & 7)) * 8;
  const u16* sF0 = wfcT + ((size_t)e * H_ + col0 + rowB) * C_ + kcB;
  const u16* sG0 = wgT + ((size_t)e * H_ + col0 + rowB) * C_ + kcB;

  f32x4 ah[4][2] = {}; f32x4 ag[4][2] = {};

  // prologue: stage tile 0 into buffer 0
  {
    u16* a = &As[0][wid * 4 * 512];
    #pragma unroll
    for (int i = 0; i < 4; ++i) gl16(sA[i], a + i * 512);
    u16* f = &Bf[0][wid * 2 * 512];
    gl16(sF0, f); gl16(sF0 + 8 * C_, f + 512);
    u16* gg = &Bg[0][wid * 2 * 512];
    gl16(sG0, gg); gl16(sG0 + 8 * C_, gg + 512);
  }

  #pragma unroll 2
  for (int t = 0; t < 16; ++t) {
    int pb = t & 1;
    if (t < 15) {
      // issue next tile into other buffer; 8 gl16 per wave stay in flight
      int kt = (t + 1) * 64;
      u16* a = &As[pb ^ 1][wid * 4 * 512];
      #pragma unroll
      for (int i = 0; i < 4; ++i) gl16(sA[i] + kt, a + i * 512);
      u16* f = &Bf[pb ^ 1][wid * 2 * 512];
      gl16(sF0 + kt, f); gl16(sF0 + 8 * C_ + kt, f + 512);
      u16* gg = &Bg[pb ^ 1][wid * 2 * 512];
      gl16(sG0 + kt, gg); gl16(sG0 + 8 * C_ + kt, gg + 512);
      asm volatile("s_waitcnt vmcnt(8)" ::: "memory");   // current tile landed
    } else {
      asm volatile("s_waitcnt vmcnt(0)" ::: "memory");   // last tile landed
    }
    __builtin_amdgcn_s_barrier();
    #pragma unroll
    for (int kk = 0; kk < 2; ++kk) {
      int so = ((kk * 4 + fq) ^ q) * 8;     // swizzled 16B slot -> u16 offset
      bf16x8 a[4], f[2], gg[2];
      #pragma unroll
      for (int m = 0; m < 4; ++m)
        a[m] = *reinterpret_cast<const bf16x8*>(&As[pb][(wr * 64 + m * 16 + fr) * 64 + so]);
      #pragma unroll
      for (int j = 0; j < 2; ++j) {
        f[j]  = *reinterpret_cast<const bf16x8*>(&Bf[pb][(wc * 32 + j * 16 + fr) * 64 + so]);
        gg[j] = *reinterpret_cast<const bf16x8*>(&Bg[pb][(wc * 32 + j * 16 + fr) * 64 + so]);
      }
      #pragma unroll
      for (int m = 0; m < 4; ++m)
        #pragma unroll
        for (int j = 0; j < 2; ++j) {
          ah[m][j] = __builtin_amdgcn_mfma_f32_16x16x32_bf16(a[m], f[j],  ah[m][j], 0, 0, 0);
          ag[m][j] = __builtin_amdgcn_mfma_f32_16x16x32_bf16(a[m], gg[j], ag[m][j], 0, 0, 0);
        }
    }
    __builtin_amdgcn_s_barrier();   // all waves done reading buf pb before overwrite
  }
  int base = offsets[g];
  #pragma unroll
  for (int m = 0; m < 4; ++m) {
    #pragma unroll
    for (int rj = 0; rj < 4; ++rj) {
      int slot = row0 + wr * 64 + m * 16 + fq * 4 + rj;
      if (slot < n) {
        size_t rowb = (size_t)(base + slot) * H_;
        #pragma unroll
        for (int j = 0; j < 2; ++j) {
          int hc = col0 + wc * 32 + j * 16 + fr;
          float h  = ah[m][j][rj] + bfc[e * H_ + hc];
          float gp = ag[m][j][rj] + bg[e * H_ + hc];
          inter[rowb + hc] = f2bf(h * gp / (1.f + expf(-gp)));   // h * silu(gp)
        }
      }
    }
  }
}

// ---------- GEMM2: obuf = inter@Wproj + bp  (non-atomic, compacted rows) ----------
// BM=128 x BN=128, BK=64, dbuf 64KB (2 blk/CU), counted vmcnt.
__global__ __launch_bounds__(256) void k_ffn2(
    const u16* __restrict__ inter, const u16* __restrict__ wpT,
    const float* __restrict__ bp,
    const int* __restrict__ counts, const int* __restrict__ offsets,
    float* __restrict__ obuf) {
  int bid = blockIdx.x;
  int e = bid & 7;
  int r = bid >> 3;                 // [0,512)
  int chunk = r >> 7;               // [0,4)  2-coltile chunk (1MB weights -> L2)
  int rr = r & 127;
  int brt = rr >> 1;                // [0,64)
  int col = chunk * 2 + (rr & 1);   // [0,8)
  int b = brt >> 3, rt = brt & 7;
  int g = b * 8 + e;
  int n = counts[g];
  int row0 = rt * 128;
  if (row0 >= n) return;
  int col0 = col * 128;
  int base = offsets[g];

  __shared__ u16 As[2][128 * 64];   // 2 x 16 KB
  __shared__ u16 Bs[2][128 * 64];   // 2 x 16 KB  total 64 KB

  int tid = threadIdx.x;
  int lane = tid & 63, wid = tid >> 6;
  int wr = wid >> 1, wc = wid & 1;
  int fr = lane & 15, fq = lane >> 4;
  int q = fr & 7;

  const u16* sA[4];
  #pragma unroll
  for (int i = 0; i < 4; ++i) {
    int ck = (wid * 4 + i) * 64 + lane;
    int row = ck >> 3;
    int kc = ((ck & 7) ^ (row & 7)) * 8;
    int slot = row0 + row;
    int rg = base + (slot < n ? slot : n - 1);   // clamp into valid compacted rows
    sA[i] = inter + (size_t)rg * H_ + kc;
  }
  int ckB = (wid * 4) * 64 + lane;
  int rowB = ckB >> 3;
  int kcB = ((ckB & 7) ^ (rowB & 7)) * 8;
  const u16* sB0 = wpT + ((size_t)e * C_ + col0 + rowB) * H_ + kcB;

  f32x4 acc[4][4] = {};

  {
    u16* a = &As[0][wid * 4 * 512];
    u16* bb = &Bs[0][wid * 4 * 512];
    #pragma unroll
    for (int i = 0; i < 4; ++i) {
      gl16(sA[i], a + i * 512);
      gl16(sB0 + (size_t)i * 8 * H_, bb + i * 512);
    }
  }

  #pragma unroll 2
  for (int t = 0; t < 32; ++t) {
    int pb = t & 1;
    if (t < 31) {
      int kt = (t + 1) * 64;
      u16* a = &As[pb ^ 1][wid * 4 * 512];
      u16* bb = &Bs[pb ^ 1][wid * 4 * 512];
      #pragma unroll
      for (int i = 0; i < 4; ++i) {
        gl16(sA[i] + kt, a + i * 512);
        gl16(sB0 + (size_t)i * 8 * H_ + kt, bb + i * 512);
      }
      asm volatile("s_waitcnt vmcnt(8)" ::: "memory");
    } else {
      asm volatile("s_waitcnt vmcnt(0)" ::: "memory");
    }
    __builtin_amdgcn_s_barrier();
    #pragma unroll
    for (int kk = 0; kk < 2; ++kk) {
      int so = ((kk * 4 + fq) ^ q) * 8;
      bf16x8 a[4], bb[4];
      #pragma unroll
      for (int m = 0; m < 4; ++m)
        a[m] = *reinterpret_cast<const bf16x8*>(&As[pb][(wr * 64 + m * 16 + fr) * 64 + so]);
      #pragma unroll
      for (int j = 0; j < 4; ++j)
        bb[j] = *reinterpret_cast<const bf16x8*>(&Bs[pb][(wc * 64 + j * 16 + fr) * 64 + so]);
      #pragma unroll
      for (int m = 0; m < 4; ++m)
        #pragma unroll
        for (int j = 0; j < 4; ++j)
          acc[m][j] = __builtin_amdgcn_mfma_f32_16x16x32_bf16(a[m], bb[j], acc[m][j], 0, 0, 0);
    }
    __builtin_amdgcn_s_barrier();
  }
  #pragma unroll
  for (int m = 0; m < 4; ++m) {
    #pragma unroll
    for (int rj = 0; rj < 4; ++rj) {
      int slot = row0 + wr * 64 + m * 16 + fq * 4 + rj;
      if (slot < n) {
        float* orow = obuf + (size_t)(base + slot) * C_;
        #pragma unroll
        for (int j = 0; j < 4; ++j) {
          int cc = col0 + wc * 64 + j * 16 + fr;
          orow[cc] = acc[m][j][rj] + bp[e * C_ + cc];
        }
      }
    }
  }
}

// ---------- combine: y[t] = p0*obuf[r0] + p1*obuf[r1] ----------
__global__ __launch_bounds__(256) void k_combine(const float* __restrict__ obuf,
                                                 const int* __restrict__ offsets,
                                                 const int* __restrict__ inv,
                                                 const float* __restrict__ pw,
                                                 float* __restrict__ y) {
  int tt = blockIdx.x;
  int c = threadIdx.x * 4;
  int i0 = inv[tt * 2 + 0], i1 = inv[tt * 2 + 1];
  int r0 = offsets[i0 >> 10] + (i0 & (T_ - 1));
  int r1 = offsets[i1 >> 10] + (i1 & (T_ - 1));
  float p0 = pw[i0], p1 = pw[i1];
  float4 a = *reinterpret_cast<const float4*>(obuf + (size_t)r0 * C_ + c);
  float4 bv = *reinterpret_cast<const float4*>(obuf + (size_t)r1 * C_ + c);
  float4 o;
  o.x = p0 * a.x + p1 * bv.x;
  o.y = p0 * a.y + p1 * bv.y;
  o.z = p0 * a.z + p1 * bv.z;
  o.w = p0 * a.w + p1 * bv.w;
  *reinterpret_cast<float4*>(y + (size_t)tt * C_ + c) = o;
}

extern "C" void kernel_launch(void* const* d_in, const int* in_sizes, int n_in,
                              void* d_out, int out_size, void* d_ws, size_t ws_size,
                              hipStream_t stream) {
  const float* x   = (const float*)d_in[0];
  const float* rw  = (const float*)d_in[1];
  const float* wfc = (const float*)d_in[2];
  const float* bfc = (const float*)d_in[3];
  const float* wg  = (const float*)d_in[4];
  const float* bg  = (const float*)d_in[5];
  const float* wp  = (const float*)d_in[6];
  const float* bp  = (const float*)d_in[7];
  float* y = (float*)d_out;

  char* ws = (char*)d_ws;
  // ws layout (bytes). obuf aliases wfcT+wgT (dead after k_ffn1); total ~177MB.
  const size_t OFF_COUNTS  = 0;                        // 64 ints
  const size_t OFF_OFFSETS = 1024;                     // 65 ints
  const size_t OFF_TOK     = 2048;                     // 256 KB
  const size_t OFF_PW      = OFF_TOK + 262144;         // 256 KB
  const size_t OFF_INV     = OFF_PW + 262144;          // 128 KB
  const size_t OFF_XB      = OFF_INV + 131072;         // 16 MB bf16 x
  const size_t OFF_WPT     = OFF_XB + (size_t)B_ * T_ * C_ * 2;     // 32 MB
  const size_t OFF_INTER   = OFF_WPT + (size_t)E_ * H_ * C_ * 2;    // 64 MB bf16
  const size_t OFF_WFCT    = OFF_INTER + (size_t)NROWS * H_ * 2;    // 32 MB
  const size_t OFF_WGT     = OFF_WFCT + (size_t)E_ * C_ * H_ * 2;   // 32 MB
  const size_t OFF_OBUF    = OFF_WFCT;                 // 64 MB f32, aliases wfcT+wgT
  int*   counts  = (int*)(ws + OFF_COUNTS);
  int*   offsets = (int*)(ws + OFF_OFFSETS);
  int*   tok     = (int*)(ws + OFF_TOK);
  float* pw      = (float*)(ws + OFF_PW);
  int*   inv     = (int*)(ws + OFF_INV);
  u16*   xb      = (u16*)(ws + OFF_XB);
  u16*   wpT     = (u16*)(ws + OFF_WPT);
  u16*   inter   = (u16*)(ws + OFF_INTER);
  u16*   wfcT    = (u16*)(ws + OFF_WFCT);
  u16*   wgT     = (u16*)(ws + OFF_WGT);
  float* obuf    = (float*)(ws + OFF_OBUF);

  hipMemsetAsync(counts, 0, 256, stream);

  k_wt<<<dim3(H_ / 64, C_ / 64, E_), 256, 0, stream>>>(wfc, wfcT, C_, H_);
  k_wt<<<dim3(H_ / 64, C_ / 64, E_), 256, 0, stream>>>(wg, wgT, C_, H_);
  k_wt<<<dim3(C_ / 64, H_ / 64, E_), 256, 0, stream>>>(wp, wpT, H_, C_);
  k_router<<<(B_ * T_) / 4, 256, 0, stream>>>(x, rw, xb, counts, tok, pw, inv);
  k_prefix<<<1, 64, 0, stream>>>(counts, offsets);
  k_ffn1<<<E_ * 8 * 64 * 4, 256, 0, stream>>>(          // 16384 blocks
      xb, wfcT, wgT, bfc, bg, counts, offsets, tok, inter);
  k_ffn2<<<E_ * 4 * 64 * 2, 256, 0, stream>>>(          // 4096 blocks
      inter, wpT, bp, counts, offsets, obuf);
  k_combine<<<B_ * T_, 256, 0, stream>>>(obuf, offsets, inv, pw, y);
  (void)in_sizes; (void)n_in; (void)ws_size;
}